// Round 1
// baseline (1484.129 us; speedup 1.0000x reference)
//
#include <hip/hip_runtime.h>

#define NN 100000
#define EE 1600000
#define GG 2048
#define EPSB 1e-5f

// ---------------- CSR build ----------------

__global__ void count_kernel(const int* __restrict__ col, int* __restrict__ cnt) {
    int e = blockIdx.x * 256 + threadIdx.x;
    if (e < EE) atomicAdd(&cnt[col[e]], 1);
}

__global__ void scanA_kernel(int* __restrict__ colptr, const int* __restrict__ cnt,
                             int* __restrict__ bsums, int n) {
    __shared__ int sh[256];
    int t = threadIdx.x;
    int i = blockIdx.x * 256 + t;
    int v = (i < n) ? cnt[i] : 0;
    sh[t] = v;
    __syncthreads();
    for (int off = 1; off < 256; off <<= 1) {
        int u = (t >= off) ? sh[t - off] : 0;
        __syncthreads();
        sh[t] += u;
        __syncthreads();
    }
    if (i < n) colptr[i] = sh[t] - v;          // exclusive within block
    if (t == 255) bsums[blockIdx.x] = sh[255]; // block total
}

__global__ void scanB_kernel(int* __restrict__ bsums, int nb) {
    __shared__ int sh[512];
    int t = threadIdx.x;
    int v = (t < nb) ? bsums[t] : 0;
    sh[t] = v;
    __syncthreads();
    for (int off = 1; off < 512; off <<= 1) {
        int u = (t >= off) ? sh[t - off] : 0;
        __syncthreads();
        sh[t] += u;
        __syncthreads();
    }
    if (t < nb) bsums[t] = sh[t] - v;          // exclusive block offsets
}

__global__ void scanC_kernel(int* __restrict__ colptr, const int* __restrict__ bsums,
                             int* __restrict__ cursor, const int* __restrict__ cnt,
                             float* __restrict__ dinv, int n) {
    int i = blockIdx.x * 256 + threadIdx.x;
    if (i < n) {
        int v = colptr[i] + bsums[blockIdx.x];
        colptr[i] = v;
        cursor[i] = v;
        dinv[i] = rsqrtf((float)(cnt[i] + 1));  // +1 self loop
    }
    if (i == 0) colptr[n] = EE;
}

__global__ void fill_kernel(const int* __restrict__ row, const int* __restrict__ col,
                            const float* __restrict__ dinv, int* __restrict__ cursor,
                            int* __restrict__ srcs, float* __restrict__ wsrt) {
    int e = blockIdx.x * 256 + threadIdx.x;
    if (e < EE) {
        int r = row[e], c = col[e];
        int p = atomicAdd(&cursor[c], 1);
        srcs[p] = r;
        wsrt[p] = dinv[r] * dinv[c];
    }
}

// ---------------- aggregation: out[i] = sum_e w_e * f(X[src_e]) + dinv[i]^2 * f(X[i]) ----------------

template <int F, bool TR>
__global__ void agg_kernel(const float* __restrict__ X, float* __restrict__ out,
                           const int* __restrict__ colptr, const int* __restrict__ srcs,
                           const float* __restrict__ wsrt, const float* __restrict__ dinv,
                           const float* __restrict__ sc, const float* __restrict__ shf) {
    int i = blockIdx.x;
    int f = threadIdx.x;
    int beg = colptr[i], end = colptr[i + 1];
    float scf = 0.f, shv = 0.f;
    if (TR) { scf = sc[f]; shv = shf[f]; }
    float acc = 0.f;
    for (int e = beg; e < end; ++e) {
        int s = srcs[e];
        float w = wsrt[e];
        float v = X[(size_t)s * F + f];
        if (TR) v = fmaxf(fmaf(scf, v, shv), 0.f);
        acc += w * v;
    }
    float di = dinv[i];
    float v = X[(size_t)i * F + f];
    if (TR) v = fmaxf(fmaf(scf, v, shv), 0.f);
    out[(size_t)i * F + f] = acc + di * di * v;
}

// ---------------- GEMM: C[M,Nout] = f(A[M,K]) @ W[K,Nout] ----------------

template <bool TR>
__global__ __launch_bounds__(256) void gemm_kernel(
        const float* __restrict__ A, const float* __restrict__ W, float* __restrict__ C,
        int M, int K, int Nout, const float* __restrict__ sc, const float* __restrict__ shf) {
    __shared__ float As[16][68];
    __shared__ float Ws[16][64];
    const int tid = threadIdx.x;
    const int tx = tid & 15, ty = tid >> 4;
    const int row0 = blockIdx.x * 64;
    const int col0 = blockIdx.y * 64;
    float acc[4][4] = {};
    const int ar = tid >> 2;        // A row within tile 0..63
    const int ak = (tid & 3) * 4;   // A k within tile
    const int wk = tid >> 4;        // W k within tile 0..15
    const int wn = (tid & 15) * 4;  // W col within tile

    for (int k0 = 0; k0 < K; k0 += 16) {
        float4 av = make_float4(0.f, 0.f, 0.f, 0.f);
        int arow = row0 + ar;
        if (arow < M) av = *(const float4*)&A[(size_t)arow * K + k0 + ak];
        if (TR) {
            float4 s4 = *(const float4*)&sc[k0 + ak];
            float4 h4 = *(const float4*)&shf[k0 + ak];
            av.x = fmaxf(fmaf(s4.x, av.x, h4.x), 0.f);
            av.y = fmaxf(fmaf(s4.y, av.y, h4.y), 0.f);
            av.z = fmaxf(fmaf(s4.z, av.z, h4.z), 0.f);
            av.w = fmaxf(fmaf(s4.w, av.w, h4.w), 0.f);
        }
        As[ak + 0][ar] = av.x;
        As[ak + 1][ar] = av.y;
        As[ak + 2][ar] = av.z;
        As[ak + 3][ar] = av.w;
        *(float4*)&Ws[wk][wn] = *(const float4*)&W[(size_t)(k0 + wk) * Nout + col0 + wn];
        __syncthreads();
#pragma unroll
        for (int k = 0; k < 16; ++k) {
            float4 a = *(const float4*)&As[k][ty * 4];
            float4 b = *(const float4*)&Ws[k][tx * 4];
            float aa[4] = {a.x, a.y, a.z, a.w};
            float bb[4] = {b.x, b.y, b.z, b.w};
#pragma unroll
            for (int i = 0; i < 4; ++i)
#pragma unroll
                for (int j = 0; j < 4; ++j) acc[i][j] = fmaf(aa[i], bb[j], acc[i][j]);
        }
        __syncthreads();
    }
#pragma unroll
    for (int i = 0; i < 4; ++i) {
        int r = row0 + ty * 4 + i;
        if (r < M) {
            float4 o = make_float4(acc[i][0], acc[i][1], acc[i][2], acc[i][3]);
            *(float4*)&C[(size_t)r * Nout + col0 + tx * 4] = o;
        }
    }
}

// ---------------- column stats (sum, sumsq) ----------------

__global__ void stats_kernel(const float* __restrict__ Z, int Mrows, int F,
                             float* __restrict__ sums) {
    int f = threadIdx.x;  // blockDim == F
    float s = 0.f, q = 0.f;
    for (int r = blockIdx.x; r < Mrows; r += gridDim.x) {
        float v = Z[(size_t)r * F + f];
        s += v;
        q += v * v;
    }
    atomicAdd(&sums[f], s);
    atomicAdd(&sums[F + f], q);
}

__global__ void finalize_kernel(const float* __restrict__ sums, int F,
                                const float* __restrict__ g, const float* __restrict__ be,
                                float* __restrict__ sc, float* __restrict__ shf) {
    int f = threadIdx.x;
    if (f < F) {
        float m = sums[f] * (1.f / NN);
        float v = sums[F + f] * (1.f / NN) - m * m;
        float s = g[f] * rsqrtf(v + EPSB);
        sc[f] = s;
        shf[f] = be[f] - m * s;
    }
}

// ---------------- pool: out[g] = mean over nodes of (s*z + t), 0 if empty ----------------

__global__ void pool_kernel(const float* __restrict__ Z, const int* __restrict__ batch,
                            const float* __restrict__ sc, const float* __restrict__ shf,
                            float* __restrict__ out) {
    int gph = blockIdx.x;
    int f = threadIdx.x;  // 128
    __shared__ int sb, se;
    if (f == 0) {
        int lo = 0, hi = NN;
        while (lo < hi) { int mid = (lo + hi) >> 1; if (batch[mid] < gph) lo = mid + 1; else hi = mid; }
        sb = lo;
        hi = NN;
        while (lo < hi) { int mid = (lo + hi) >> 1; if (batch[mid] < gph + 1) lo = mid + 1; else hi = mid; }
        se = lo;
    }
    __syncthreads();
    int beg = sb, end = se;
    float acc = 0.f;
    for (int r = beg; r < end; ++r) acc += Z[(size_t)r * 128 + f];
    float res = 0.f;
    int c = end - beg;
    if (c > 0) res = fmaf(sc[f], acc / (float)c, shf[f]);
    out[(size_t)gph * 128 + f] = res;
}

// ---------------- launch ----------------

extern "C" void kernel_launch(void* const* d_in, const int* in_sizes, int n_in,
                              void* d_out, int out_size, void* d_ws, size_t ws_size,
                              hipStream_t stream) {
    const float* x    = (const float*)d_in[0];
    const int*   row  = (const int*)d_in[1];
    const int*   col  = (const int*)d_in[2];
    const int*   batch = (const int*)d_in[3];
    const float* W1 = (const float*)d_in[4];
    const float* g1 = (const float*)d_in[6];
    const float* be1 = (const float*)d_in[7];
    const float* W2 = (const float*)d_in[8];
    const float* g2 = (const float*)d_in[10];
    const float* be2 = (const float*)d_in[11];
    const float* W3 = (const float*)d_in[12];
    const float* g3 = (const float*)d_in[14];
    const float* be3 = (const float*)d_in[15];
    float* out = (float*)d_out;

    char* ws = (char*)d_ws;
    size_t off = 0;
    auto alloc = [&](size_t bytes) { size_t o = off; off += (bytes + 255) & ~255ULL; return o; };
    float* bufA   = (float*)(ws + alloc((size_t)NN * 256 * 4));
    float* bufB   = (float*)(ws + alloc((size_t)NN * 256 * 4));
    int*   cnt    = (int*)  (ws + alloc((size_t)NN * 4));
    int*   colptr = (int*)  (ws + alloc((size_t)(NN + 1) * 4));
    int*   cursor = (int*)  (ws + alloc((size_t)NN * 4));
    float* dinv   = (float*)(ws + alloc((size_t)NN * 4));
    int*   srcs   = (int*)  (ws + alloc((size_t)EE * 4));
    float* wsrt   = (float*)(ws + alloc((size_t)EE * 4));
    int*   bsums  = (int*)  (ws + alloc(1024 * 4));
    float* stats  = (float*)(ws + alloc(6 * 256 * 4));  // [sum,sq] x 3 layers, 512 floats apart
    float* scbuf  = (float*)(ws + alloc(6 * 256 * 4));  // [s,t] x 3 layers, 512 floats apart

    hipMemsetAsync(cnt, 0, (size_t)NN * 4, stream);
    hipMemsetAsync(stats, 0, 6 * 256 * 4, stream);

    const int nScanBlocks = (NN + 255) / 256;  // 391
    count_kernel<<<(EE + 255) / 256, 256, 0, stream>>>(col, cnt);
    scanA_kernel<<<nScanBlocks, 256, 0, stream>>>(colptr, cnt, bsums, NN);
    scanB_kernel<<<1, 512, 0, stream>>>(bsums, nScanBlocks);
    scanC_kernel<<<nScanBlocks, 256, 0, stream>>>(colptr, bsums, cursor, cnt, dinv, NN);
    fill_kernel<<<(EE + 255) / 256, 256, 0, stream>>>(row, col, dinv, cursor, srcs, wsrt);

    const int mBlocks = (NN + 63) / 64;  // 1563

    // Layer 1: T1 = S@x (128-wide), Z1 = T1@W1 (256-wide)
    agg_kernel<128, false><<<NN, 128, 0, stream>>>(x, bufA, colptr, srcs, wsrt, dinv, nullptr, nullptr);
    gemm_kernel<false><<<dim3(mBlocks, 4), 256, 0, stream>>>(bufA, W1, bufB, NN, 128, 256, nullptr, nullptr);
    stats_kernel<<<512, 256, 0, stream>>>(bufB, NN, 256, stats + 0);
    finalize_kernel<<<1, 256, 0, stream>>>(stats + 0, 256, g1, be1, scbuf + 0, scbuf + 256);

    // Layer 2: T2 = S@relu(bn1(Z1)), Z2 = T2@W2
    agg_kernel<256, true><<<NN, 256, 0, stream>>>(bufB, bufA, colptr, srcs, wsrt, dinv, scbuf + 0, scbuf + 256);
    gemm_kernel<false><<<dim3(mBlocks, 4), 256, 0, stream>>>(bufA, W2, bufB, NN, 256, 256, nullptr, nullptr);
    stats_kernel<<<512, 256, 0, stream>>>(bufB, NN, 256, stats + 512);
    finalize_kernel<<<1, 256, 0, stream>>>(stats + 512, 256, g2, be2, scbuf + 512, scbuf + 768);

    // Layer 3: H3 = relu(bn2(Z2))@W3 (128-wide), Z3 = S@H3
    gemm_kernel<true><<<dim3(mBlocks, 2), 256, 0, stream>>>(bufB, W3, bufA, NN, 256, 128, scbuf + 512, scbuf + 768);
    agg_kernel<128, false><<<NN, 128, 0, stream>>>(bufA, bufB, colptr, srcs, wsrt, dinv, nullptr, nullptr);
    stats_kernel<<<512, 128, 0, stream>>>(bufB, NN, 128, stats + 1024);
    finalize_kernel<<<1, 256, 0, stream>>>(stats + 1024, 128, g3, be3, scbuf + 1024, scbuf + 1280);

    // Pool
    pool_kernel<<<GG, 128, 0, stream>>>(bufB, batch, scbuf + 1024, scbuf + 1280, out);
}

// Round 2
// 853.554 us; speedup vs baseline: 1.7388x; 1.7388x over previous
//
#include <hip/hip_runtime.h>

#define NN 100000
#define EE 1600000
#define GG 2048
#define EPSB 1e-5f
#define MP 100096   // NN padded to multiple of 128

typedef unsigned short u16;
typedef __attribute__((ext_vector_type(8))) short short8;
typedef __attribute__((ext_vector_type(4))) float f32x4;

struct alignas(4)  u16x2 { u16 v[2]; };
struct alignas(8)  u16x4 { u16 v[4]; };
struct alignas(16) u16x8 { u16 v[8]; };

__device__ __forceinline__ float b2f(u16 u) { return __uint_as_float(((unsigned)u) << 16); }
__device__ __forceinline__ u16 f2b(float f) {
    unsigned u = __float_as_uint(f);
    return (u16)((u + 0x7FFF + ((u >> 16) & 1)) >> 16);
}
__device__ __forceinline__ void gload16(const void* g, void* l) {
    __builtin_amdgcn_global_load_lds((const __attribute__((address_space(1))) void*)g,
                                     (__attribute__((address_space(3))) void*)l, 16, 0, 0);
}

// ---------------- CSR build ----------------

__global__ void count_kernel(const int* __restrict__ col, int* __restrict__ cnt) {
    int e = blockIdx.x * 256 + threadIdx.x;
    if (e < EE) atomicAdd(&cnt[col[e]], 1);
}

__global__ void scanA_kernel(int* __restrict__ colptr, const int* __restrict__ cnt,
                             int* __restrict__ bsums, int n) {
    __shared__ int sh[256];
    int t = threadIdx.x;
    int i = blockIdx.x * 256 + t;
    int v = (i < n) ? cnt[i] : 0;
    sh[t] = v;
    __syncthreads();
    for (int off = 1; off < 256; off <<= 1) {
        int u = (t >= off) ? sh[t - off] : 0;
        __syncthreads();
        sh[t] += u;
        __syncthreads();
    }
    if (i < n) colptr[i] = sh[t] - v;
    if (t == 255) bsums[blockIdx.x] = sh[255];
}

__global__ void scanB_kernel(int* __restrict__ bsums, int nb) {
    __shared__ int sh[512];
    int t = threadIdx.x;
    int v = (t < nb) ? bsums[t] : 0;
    sh[t] = v;
    __syncthreads();
    for (int off = 1; off < 512; off <<= 1) {
        int u = (t >= off) ? sh[t - off] : 0;
        __syncthreads();
        sh[t] += u;
        __syncthreads();
    }
    if (t < nb) bsums[t] = sh[t] - v;
}

__global__ void scanC_kernel(int* __restrict__ colptr, const int* __restrict__ bsums,
                             int* __restrict__ cursor, const int* __restrict__ cnt,
                             float* __restrict__ dinv, int n) {
    int i = blockIdx.x * 256 + threadIdx.x;
    if (i < n) {
        int v = colptr[i] + bsums[blockIdx.x];
        colptr[i] = v;
        cursor[i] = v;
        dinv[i] = rsqrtf((float)(cnt[i] + 1));
    }
    if (i == 0) colptr[n] = EE;
}

__global__ void fill_kernel(const int* __restrict__ row, const int* __restrict__ col,
                            const float* __restrict__ dinv, int* __restrict__ cursor,
                            int* __restrict__ srcs, float* __restrict__ wsrt) {
    int e = blockIdx.x * 256 + threadIdx.x;
    if (e < EE) {
        int r = row[e], c = col[e];
        int p = atomicAdd(&cursor[c], 1);
        srcs[p] = r;
        wsrt[p] = dinv[r] * dinv[c];
    }
}

// ---------------- casts ----------------

__global__ void xcast_kernel(const float* __restrict__ x, u16* __restrict__ xb) {
    int idx = blockIdx.x * 256 + threadIdx.x;   // NN*128/4 chunks
    if (idx < NN * 32) {
        float4 v = ((const float4*)x)[idx];
        u16x4 o = {{f2b(v.x), f2b(v.y), f2b(v.z), f2b(v.w)}};
        ((u16x4*)xb)[idx] = o;
    }
}

// Wt[n*K + k] = bf16(W[k*Nout + n])
__global__ void wcast_kernel(const float* __restrict__ W, u16* __restrict__ Wt, int K, int Nout) {
    int idx = blockIdx.x * 256 + threadIdx.x;
    if (idx < K * Nout) {
        int n = idx / K;
        int k = idx - n * K;
        Wt[idx] = f2b(W[(size_t)k * Nout + n]);
    }
}

// ---------------- aggregation (one node per wave) ----------------
// out[i] = sum_e w_e * f(X[src_e]) + dinv[i]^2 * f(X[i]);  f = identity or relu(s*z+t)

template <int F, bool TR>
__global__ void agg_kernel(const u16* __restrict__ X, u16* __restrict__ out,
                           const int* __restrict__ colptr, const int* __restrict__ srcs,
                           const float* __restrict__ wsrt, const float* __restrict__ dinv,
                           const float* __restrict__ sc, const float* __restrict__ shf) {
    constexpr int VE = F / 64;   // feats per lane: 4 (F=256) or 2 (F=128)
    int node = blockIdx.x * 4 + (threadIdx.x >> 6);
    if (node >= NN) return;
    int l = threadIdx.x & 63;
    int f0 = l * VE;
    float s_[VE], t_[VE];
    if (TR) {
#pragma unroll
        for (int j = 0; j < VE; ++j) { s_[j] = sc[f0 + j]; t_[j] = shf[f0 + j]; }
    }
    float acc[VE] = {};
    int e = colptr[node], end = colptr[node + 1];

    auto fetch = [&](int s, u16* u) {
        if (VE == 4) *(u16x4*)u = *(const u16x4*)(X + (size_t)s * F + f0);
        else         *(u16x2*)u = *(const u16x2*)(X + (size_t)s * F + f0);
    };
    auto accum = [&](const u16* u, float w) {
#pragma unroll
        for (int j = 0; j < VE; ++j) {
            float v = b2f(u[j]);
            if (TR) v = fmaxf(fmaf(s_[j], v, t_[j]), 0.f);
            acc[j] = fmaf(w, v, acc[j]);
        }
    };

    while (e + 1 < end) {
        int s0 = srcs[e], s1 = srcs[e + 1];
        float w0 = wsrt[e], w1 = wsrt[e + 1];
        u16 u0[VE], u1[VE];
        fetch(s0, u0);
        fetch(s1, u1);
        accum(u0, w0);
        accum(u1, w1);
        e += 2;
    }
    if (e < end) {
        u16 u0[VE];
        fetch(srcs[e], u0);
        accum(u0, wsrt[e]);
    }
    float di = dinv[node];
    u16 us[VE];
    fetch(node, us);
    accum(us, di * di);
    if (VE == 4) {
        u16x4 o = {{f2b(acc[0]), f2b(acc[1]), f2b(acc[2]), f2b(acc[3])}};
        *(u16x4*)(out + (size_t)node * F + f0) = o;
    } else {
        u16x2 o = {{f2b(acc[0]), f2b(acc[1])}};
        *(u16x2*)(out + (size_t)node * F + f0) = o;
    }
}

// ---------------- MFMA GEMM: C[MP,Nout](bf16) = A[MP,Kdim](bf16) @ Wt[Nout,Kdim]^T ----------------

__global__ __launch_bounds__(256) void gemm_kernel(const u16* __restrict__ A,
                                                   const u16* __restrict__ Wt,
                                                   u16* __restrict__ C,
                                                   int Kdim, int Nout) {
    __shared__ u16 As[128 * 64];   // [row][k] rows of A tile
    __shared__ u16 Bs[128 * 64];   // [col][k] cols of W tile
    const int tid = threadIdx.x;
    const int w = tid >> 6, l = tid & 63;
    const int row0 = blockIdx.x * 128;
    const int col0 = blockIdx.y * 128;
    const int srow = w * 32 + (l >> 3);   // staging row, + j*8
    const int skel = (l & 7) * 8;         // staging k-elem offset
    const u16* Asrc = A + (size_t)(row0 + srow) * Kdim + skel;
    const u16* Bsrc = Wt + (size_t)(col0 + srow) * Kdim + skel;
    u16* AsBase = &As[w * 2048];          // + j*512; HW adds lane*16B
    u16* BsBase = &Bs[w * 2048];
    const int wr = (w >> 1) * 64, wc = (w & 1) * 64;
    f32x4 acc[4][4] = {};

    for (int k0 = 0; k0 < Kdim; k0 += 64) {
#pragma unroll
        for (int j = 0; j < 4; ++j) {
            gload16(Asrc + (size_t)(j * 8) * Kdim + k0, AsBase + j * 512);
            gload16(Bsrc + (size_t)(j * 8) * Kdim + k0, BsBase + j * 512);
        }
        __syncthreads();
#pragma unroll
        for (int ks = 0; ks < 2; ++ks) {
            short8 a[4], b[4];
#pragma unroll
            for (int mi = 0; mi < 4; ++mi)
                a[mi] = *(const short8*)&As[(wr + mi * 16 + (l & 15)) * 64 + ks * 32 + (l >> 4) * 8];
#pragma unroll
            for (int ni = 0; ni < 4; ++ni)
                b[ni] = *(const short8*)&Bs[(wc + ni * 16 + (l & 15)) * 64 + ks * 32 + (l >> 4) * 8];
#pragma unroll
            for (int mi = 0; mi < 4; ++mi)
#pragma unroll
                for (int ni = 0; ni < 4; ++ni)
                    acc[mi][ni] = __builtin_amdgcn_mfma_f32_16x16x32_bf16(a[mi], b[ni], acc[mi][ni], 0, 0, 0);
        }
        __syncthreads();
    }
    const int cr = (l >> 4) * 4, cc = l & 15;
#pragma unroll
    for (int mi = 0; mi < 4; ++mi) {
#pragma unroll
        for (int j = 0; j < 4; ++j) {
            int r = row0 + wr + mi * 16 + cr + j;
            if (r < NN) {
#pragma unroll
                for (int ni = 0; ni < 4; ++ni)
                    C[(size_t)r * Nout + col0 + wc + ni * 16 + cc] = f2b(acc[mi][ni][j]);
            }
        }
    }
}

// ---------------- BN2+ReLU materialization ----------------

__global__ void h2_kernel(const u16* __restrict__ Z, u16* __restrict__ H,
                          const float* __restrict__ sc, const float* __restrict__ shf) {
    int idx = blockIdx.x * 256 + threadIdx.x;   // NN*256/8 chunks
    if (idx >= NN * 32) return;
    int f0 = (idx & 31) * 8;
    u16x8 z = *(const u16x8*)(Z + (size_t)idx * 8);
    u16x8 o;
#pragma unroll
    for (int j = 0; j < 8; ++j) {
        float v = b2f(z.v[j]);
        v = fmaxf(fmaf(sc[f0 + j], v, shf[f0 + j]), 0.f);
        o.v[j] = f2b(v);
    }
    *(u16x8*)(H + (size_t)idx * 8) = o;
}

// ---------------- column stats ----------------

__global__ void stats_kernel(const u16* __restrict__ Z, int F, float* __restrict__ sums) {
    int f = threadIdx.x;   // blockDim == F
    float s = 0.f, q = 0.f;
    for (int r = blockIdx.x; r < NN; r += gridDim.x) {
        float v = b2f(Z[(size_t)r * F + f]);
        s += v;
        q += v * v;
    }
    atomicAdd(&sums[f], s);
    atomicAdd(&sums[F + f], q);
}

__global__ void finalize_kernel(const float* __restrict__ sums, int F,
                                const float* __restrict__ g, const float* __restrict__ be,
                                float* __restrict__ sc, float* __restrict__ shf) {
    int f = threadIdx.x;
    if (f < F) {
        float m = sums[f] * (1.f / NN);
        float v = sums[F + f] * (1.f / NN) - m * m;
        float s = g[f] * rsqrtf(v + EPSB);
        sc[f] = s;
        shf[f] = be[f] - m * s;
    }
}

// ---------------- pool ----------------

__global__ void pool_kernel(const u16* __restrict__ Z, const int* __restrict__ batch,
                            const float* __restrict__ sc, const float* __restrict__ shf,
                            float* __restrict__ out) {
    int gph = blockIdx.x;
    int f = threadIdx.x;   // 128
    __shared__ int sb, se;
    if (f == 0) {
        int lo = 0, hi = NN;
        while (lo < hi) { int mid = (lo + hi) >> 1; if (batch[mid] < gph) lo = mid + 1; else hi = mid; }
        sb = lo;
        hi = NN;
        while (lo < hi) { int mid = (lo + hi) >> 1; if (batch[mid] < gph + 1) lo = mid + 1; else hi = mid; }
        se = lo;
    }
    __syncthreads();
    int beg = sb, end = se;
    float acc = 0.f;
    for (int r = beg; r < end; ++r) acc += b2f(Z[(size_t)r * 128 + f]);
    float res = 0.f;
    int c = end - beg;
    if (c > 0) res = fmaf(sc[f], acc / (float)c, shf[f]);
    out[(size_t)gph * 128 + f] = res;
}

// ---------------- launch ----------------

extern "C" void kernel_launch(void* const* d_in, const int* in_sizes, int n_in,
                              void* d_out, int out_size, void* d_ws, size_t ws_size,
                              hipStream_t stream) {
    const float* x     = (const float*)d_in[0];
    const int*   row   = (const int*)d_in[1];
    const int*   col   = (const int*)d_in[2];
    const int*   batch = (const int*)d_in[3];
    const float* W1 = (const float*)d_in[4];
    const float* g1 = (const float*)d_in[6];
    const float* be1 = (const float*)d_in[7];
    const float* W2 = (const float*)d_in[8];
    const float* g2 = (const float*)d_in[10];
    const float* be2 = (const float*)d_in[11];
    const float* W3 = (const float*)d_in[12];
    const float* g3 = (const float*)d_in[14];
    const float* be3 = (const float*)d_in[15];
    float* out = (float*)d_out;

    char* ws = (char*)d_ws;
    size_t off = 0;
    auto alloc = [&](size_t bytes) { size_t o = off; off += (bytes + 255) & ~255ULL; return o; };
    u16*   bufA   = (u16*)  (ws + alloc((size_t)MP * 256 * 2));
    u16*   bufB   = (u16*)  (ws + alloc((size_t)MP * 256 * 2));
    u16*   xb     = (u16*)  (ws + alloc((size_t)MP * 128 * 2));
    u16*   Wt1    = (u16*)  (ws + alloc(128 * 256 * 2));
    u16*   Wt2    = (u16*)  (ws + alloc(256 * 256 * 2));
    u16*   Wt3    = (u16*)  (ws + alloc(256 * 128 * 2));
    int*   cnt    = (int*)  (ws + alloc((size_t)NN * 4));
    int*   colptr = (int*)  (ws + alloc((size_t)(NN + 1) * 4));
    int*   cursor = (int*)  (ws + alloc((size_t)NN * 4));
    float* dinv   = (float*)(ws + alloc((size_t)NN * 4));
    int*   srcs   = (int*)  (ws + alloc((size_t)EE * 4));
    float* wsrt   = (float*)(ws + alloc((size_t)EE * 4));
    int*   bsums  = (int*)  (ws + alloc(1024 * 4));
    float* stats  = (float*)(ws + alloc(6 * 256 * 4));
    float* scbuf  = (float*)(ws + alloc(6 * 256 * 4));

    hipMemsetAsync(cnt, 0, (size_t)NN * 4, stream);
    hipMemsetAsync(stats, 0, 6 * 256 * 4, stream);

    const int nScanBlocks = (NN + 255) / 256;
    count_kernel<<<(EE + 255) / 256, 256, 0, stream>>>(col, cnt);
    scanA_kernel<<<nScanBlocks, 256, 0, stream>>>(colptr, cnt, bsums, NN);
    scanB_kernel<<<1, 512, 0, stream>>>(bsums, nScanBlocks);
    scanC_kernel<<<nScanBlocks, 256, 0, stream>>>(colptr, bsums, cursor, cnt, dinv, NN);
    fill_kernel<<<(EE + 255) / 256, 256, 0, stream>>>(row, col, dinv, cursor, srcs, wsrt);

    xcast_kernel<<<(NN * 32 + 255) / 256, 256, 0, stream>>>(x, xb);
    wcast_kernel<<<(128 * 256 + 255) / 256, 256, 0, stream>>>(W1, Wt1, 128, 256);
    wcast_kernel<<<(256 * 256 + 255) / 256, 256, 0, stream>>>(W2, Wt2, 256, 256);
    wcast_kernel<<<(256 * 128 + 255) / 256, 256, 0, stream>>>(W3, Wt3, 256, 128);

    const int aggBlocks = (NN + 3) / 4;           // 25000
    const int mBlocks = MP / 128;                 // 782

    // Layer 1: T1 = S@xb (128), Z1 = T1@W1 (256)
    agg_kernel<128, false><<<aggBlocks, 256, 0, stream>>>(xb, bufA, colptr, srcs, wsrt, dinv, nullptr, nullptr);
    gemm_kernel<<<dim3(mBlocks, 2), 256, 0, stream>>>(bufA, Wt1, bufB, 128, 256);
    stats_kernel<<<512, 256, 0, stream>>>(bufB, 256, stats + 0);
    finalize_kernel<<<1, 256, 0, stream>>>(stats + 0, 256, g1, be1, scbuf + 0, scbuf + 256);

    // Layer 2: T2 = S@relu(bn1(Z1)), Z2 = T2@W2
    agg_kernel<256, true><<<aggBlocks, 256, 0, stream>>>(bufB, bufA, colptr, srcs, wsrt, dinv, scbuf + 0, scbuf + 256);
    gemm_kernel<<<dim3(mBlocks, 2), 256, 0, stream>>>(bufA, Wt2, bufB, 256, 256);
    stats_kernel<<<512, 256, 0, stream>>>(bufB, 256, stats + 512);
    finalize_kernel<<<1, 256, 0, stream>>>(stats + 512, 256, g2, be2, scbuf + 512, scbuf + 768);

    // Layer 3: H2 = relu(bn2(Z2)), H3 = H2@W3 (128), Z3 = S@H3
    h2_kernel<<<(NN * 32 + 255) / 256, 256, 0, stream>>>(bufB, bufA, scbuf + 512, scbuf + 768);
    gemm_kernel<<<dim3(mBlocks, 1), 256, 0, stream>>>(bufA, Wt3, bufB, 256, 128);
    agg_kernel<128, false><<<aggBlocks, 256, 0, stream>>>(bufB, bufA, colptr, srcs, wsrt, dinv, nullptr, nullptr);
    stats_kernel<<<512, 128, 0, stream>>>(bufA, 128, stats + 1024);
    finalize_kernel<<<1, 256, 0, stream>>>(stats + 1024, 128, g3, be3, scbuf + 1024, scbuf + 1280);

    pool_kernel<<<GG, 128, 0, stream>>>(bufA, batch, scbuf + 1024, scbuf + 1280, out);
}

// Round 3
// 722.450 us; speedup vs baseline: 2.0543x; 1.1815x over previous
//
#include <hip/hip_runtime.h>

#define NN 100000
#define EE 1600000
#define GG 2048
#define EPSB 1e-5f
#define MP 100096   // NN padded to multiple of 128
#define MBLK (MP / 128)   // 782

typedef unsigned short u16;
typedef __attribute__((ext_vector_type(8))) short short8;
typedef __attribute__((ext_vector_type(4))) float f32x4;

struct alignas(4)  u16x2 { u16 v[2]; };
struct alignas(8)  u16x4 { u16 v[4]; };
struct alignas(16) u16x8 { u16 v[8]; };

__device__ __forceinline__ float b2f(u16 u) { return __uint_as_float(((unsigned)u) << 16); }
__device__ __forceinline__ u16 f2b(float f) {
    unsigned u = __float_as_uint(f);
    return (u16)((u + 0x7FFF + ((u >> 16) & 1)) >> 16);
}
__device__ __forceinline__ void gload16(const void* g, void* l) {
    __builtin_amdgcn_global_load_lds((const __attribute__((address_space(1))) void*)g,
                                     (__attribute__((address_space(3))) void*)l, 16, 0, 0);
}

// ---------------- CSR build ----------------

__global__ void count_kernel(const int* __restrict__ col, int* __restrict__ cnt) {
    int e = blockIdx.x * 256 + threadIdx.x;
    if (e < EE) atomicAdd(&cnt[col[e]], 1);
}

__global__ void scanA_kernel(int* __restrict__ colptr, const int* __restrict__ cnt,
                             int* __restrict__ bsums, int n) {
    __shared__ int sh[256];
    int t = threadIdx.x;
    int i = blockIdx.x * 256 + t;
    int v = (i < n) ? cnt[i] : 0;
    sh[t] = v;
    __syncthreads();
    for (int off = 1; off < 256; off <<= 1) {
        int u = (t >= off) ? sh[t - off] : 0;
        __syncthreads();
        sh[t] += u;
        __syncthreads();
    }
    if (i < n) colptr[i] = sh[t] - v;
    if (t == 255) bsums[blockIdx.x] = sh[255];
}

__global__ void scanB_kernel(int* __restrict__ bsums, int nb) {
    __shared__ int sh[512];
    int t = threadIdx.x;
    int v = (t < nb) ? bsums[t] : 0;
    sh[t] = v;
    __syncthreads();
    for (int off = 1; off < 512; off <<= 1) {
        int u = (t >= off) ? sh[t - off] : 0;
        __syncthreads();
        sh[t] += u;
        __syncthreads();
    }
    if (t < nb) bsums[t] = sh[t] - v;
}

__global__ void scanC_kernel(int* __restrict__ colptr, const int* __restrict__ bsums,
                             int* __restrict__ cursor, const int* __restrict__ cnt,
                             float* __restrict__ dinv, int n) {
    int i = blockIdx.x * 256 + threadIdx.x;
    if (i < n) {
        int v = colptr[i] + bsums[blockIdx.x];
        colptr[i] = v;
        cursor[i] = v;
        dinv[i] = rsqrtf((float)(cnt[i] + 1));
    }
    if (i == 0) colptr[n] = EE;
}

__global__ void fill_kernel(const int* __restrict__ row, const int* __restrict__ col,
                            int* __restrict__ cursor, int* __restrict__ srcs) {
    int e = blockIdx.x * 256 + threadIdx.x;
    if (e < EE) {
        int r = row[e], c = col[e];
        int p = atomicAdd(&cursor[c], 1);
        srcs[p] = r;
    }
}

// ---------------- casts ----------------

__global__ void xcast_kernel(const float* __restrict__ x, u16* __restrict__ xb) {
    int idx = blockIdx.x * 256 + threadIdx.x;
    if (idx < NN * 32) {
        float4 v = ((const float4*)x)[idx];
        u16x4 o = {{f2b(v.x), f2b(v.y), f2b(v.z), f2b(v.w)}};
        ((u16x4*)xb)[idx] = o;
    }
}

// Wt[n*K + k] = bf16(W[k*Nout + n])
__global__ void wcast_kernel(const float* __restrict__ W, u16* __restrict__ Wt, int K, int Nout) {
    int idx = blockIdx.x * 256 + threadIdx.x;
    if (idx < K * Nout) {
        int n = idx / K;
        int k = idx - n * K;
        Wt[idx] = f2b(W[(size_t)k * Nout + n]);
    }
}

// ---------------- aggregation (one node per wave, shfl-batched edges) ----------------
// out[i] = dinv[i] * ( sum_e dinv[src_e]*X[src_e] + dinv[i]*X[i] )

template <int F>
__global__ void agg_kernel(const u16* __restrict__ X, u16* __restrict__ out,
                           const int* __restrict__ colptr, const int* __restrict__ srcs,
                           const float* __restrict__ dinv) {
    constexpr int VE = F / 64;   // 4 (F=256) or 2 (F=128)
    int node = blockIdx.x * 4 + (threadIdx.x >> 6);
    if (node >= NN) return;
    int l = threadIdx.x & 63;
    int f0 = l * VE;
    float acc[VE] = {};
    int beg = colptr[node], end = colptr[node + 1];

    auto fetch = [&](int s, u16* u) {
        if (VE == 4) *(u16x4*)u = *(const u16x4*)(X + (size_t)s * F + f0);
        else         *(u16x2*)u = *(const u16x2*)(X + (size_t)s * F + f0);
    };
    auto accum = [&](const u16* u, float w) {
#pragma unroll
        for (int j = 0; j < VE; ++j) acc[j] = fmaf(w, b2f(u[j]), acc[j]);
    };

    for (int e0 = beg; e0 < end; e0 += 64) {
        int take = end - e0;
        if (take > 64) take = 64;
        int sv = 0;
        float wv = 0.f;
        if (l < take) { sv = srcs[e0 + l]; wv = dinv[sv]; }
        int j = 0;
        for (; j + 3 < take; j += 4) {
            int s0 = __shfl(sv, j), s1 = __shfl(sv, j + 1);
            int s2 = __shfl(sv, j + 2), s3 = __shfl(sv, j + 3);
            float w0 = __shfl(wv, j), w1 = __shfl(wv, j + 1);
            float w2 = __shfl(wv, j + 2), w3 = __shfl(wv, j + 3);
            u16 u0[VE], u1[VE], u2[VE], u3[VE];
            fetch(s0, u0); fetch(s1, u1); fetch(s2, u2); fetch(s3, u3);
            accum(u0, w0); accum(u1, w1); accum(u2, w2); accum(u3, w3);
        }
        for (; j < take; ++j) {
            int s0 = __shfl(sv, j);
            float w0 = __shfl(wv, j);
            u16 u0[VE];
            fetch(s0, u0);
            accum(u0, w0);
        }
    }
    float di = dinv[node];
    u16 us[VE];
    fetch(node, us);
    accum(us, di);
    if (VE == 4) {
        u16x4 o = {{f2b(di * acc[0]), f2b(di * acc[1]), f2b(di * acc[2]), f2b(di * acc[3])}};
        *(u16x4*)(out + (size_t)node * F + f0) = o;
    } else {
        u16x2 o = {{f2b(di * acc[0]), f2b(di * acc[1])}};
        *(u16x2*)(out + (size_t)node * F + f0) = o;
    }
}

// ---------------- MFMA GEMM: C[MP,Nout](bf16) = A[MP,Kdim] @ Wt[Nout,Kdim]^T ----------------
// STATS: also emit per-block column (sum, sumsq) partials of the fp32 accumulators.

template <bool STATS>
__global__ __launch_bounds__(256) void gemm_kernel(const u16* __restrict__ A,
                                                   const u16* __restrict__ Wt,
                                                   u16* __restrict__ C,
                                                   int Kdim, int Nout,
                                                   float* __restrict__ gs) {
    __shared__ u16 As[128 * 64];
    __shared__ u16 Bs[128 * 64];
    __shared__ float sbuf[2][128];
    const int tid = threadIdx.x;
    const int w = tid >> 6, l = tid & 63;
    const int row0 = blockIdx.x * 128;
    const int col0 = blockIdx.y * 128;
    const int srow = w * 32 + (l >> 3);
    const int skel = (l & 7) * 8;
    const u16* Asrc = A + (size_t)(row0 + srow) * Kdim + skel;
    const u16* Bsrc = Wt + (size_t)(col0 + srow) * Kdim + skel;
    u16* AsBase = &As[w * 2048];
    u16* BsBase = &Bs[w * 2048];
    const int wr = (w >> 1) * 64, wc = (w & 1) * 64;
    f32x4 acc[4][4] = {};
    if (STATS && tid < 128) { sbuf[0][tid] = 0.f; sbuf[1][tid] = 0.f; }

    for (int k0 = 0; k0 < Kdim; k0 += 64) {
#pragma unroll
        for (int j = 0; j < 4; ++j) {
            gload16(Asrc + (size_t)(j * 8) * Kdim + k0, AsBase + j * 512);
            gload16(Bsrc + (size_t)(j * 8) * Kdim + k0, BsBase + j * 512);
        }
        __syncthreads();
#pragma unroll
        for (int ks = 0; ks < 2; ++ks) {
            short8 a[4], b[4];
#pragma unroll
            for (int mi = 0; mi < 4; ++mi)
                a[mi] = *(const short8*)&As[(wr + mi * 16 + (l & 15)) * 64 + ks * 32 + (l >> 4) * 8];
#pragma unroll
            for (int ni = 0; ni < 4; ++ni)
                b[ni] = *(const short8*)&Bs[(wc + ni * 16 + (l & 15)) * 64 + ks * 32 + (l >> 4) * 8];
#pragma unroll
            for (int mi = 0; mi < 4; ++mi)
#pragma unroll
                for (int ni = 0; ni < 4; ++ni)
                    acc[mi][ni] = __builtin_amdgcn_mfma_f32_16x16x32_bf16(a[mi], b[ni], acc[mi][ni], 0, 0, 0);
        }
        __syncthreads();
    }
    const int cr = (l >> 4) * 4, cc = l & 15;
#pragma unroll
    for (int mi = 0; mi < 4; ++mi) {
#pragma unroll
        for (int j = 0; j < 4; ++j) {
            int r = row0 + wr + mi * 16 + cr + j;
#pragma unroll
            for (int ni = 0; ni < 4; ++ni)
                C[(size_t)r * Nout + col0 + wc + ni * 16 + cc] = f2b(acc[mi][ni][j]);
        }
    }
    if (STATS) {
#pragma unroll
        for (int ni = 0; ni < 4; ++ni) {
            float s = 0.f, q = 0.f;
#pragma unroll
            for (int mi = 0; mi < 4; ++mi)
#pragma unroll
                for (int jj = 0; jj < 4; ++jj) {
                    float v = acc[mi][ni][jj];
                    s += v;
                    q += v * v;
                }
            s += __shfl_xor(s, 16); s += __shfl_xor(s, 32);
            q += __shfl_xor(q, 16); q += __shfl_xor(q, 32);
            if (l < 16) {
                atomicAdd(&sbuf[0][wc + ni * 16 + l], s);
                atomicAdd(&sbuf[1][wc + ni * 16 + l], q);
            }
        }
        __syncthreads();
        if (tid < 128) {
            size_t base = (size_t)(blockIdx.y * gridDim.x + blockIdx.x) * 256;
            gs[base + tid] = sbuf[0][tid];
            gs[base + 128 + tid] = sbuf[1][tid];
        }
    }
}

__global__ void statreduce_kernel(const float* __restrict__ gs, float* __restrict__ sums, int F) {
    int which = blockIdx.x;       // 0 sum, 1 sumsq
    int by = blockIdx.y;
    int c = threadIdx.x;          // 128
    float s = 0.f;
    for (int bx = 0; bx < MBLK; ++bx)
        s += gs[(size_t)(by * MBLK + bx) * 256 + which * 128 + c];
    sums[which * F + by * 128 + c] = s;
}

// ---------------- BN+ReLU materialization (in place) ----------------

__global__ void hrelu_kernel(u16* __restrict__ Z,
                             const float* __restrict__ sc, const float* __restrict__ shf) {
    int idx = blockIdx.x * 256 + threadIdx.x;
    if (idx >= NN * 32) return;
    int f0 = (idx & 31) * 8;
    float4 s0 = *(const float4*)&sc[f0], s1 = *(const float4*)&sc[f0 + 4];
    float4 t0 = *(const float4*)&shf[f0], t1 = *(const float4*)&shf[f0 + 4];
    float sa[8] = {s0.x, s0.y, s0.z, s0.w, s1.x, s1.y, s1.z, s1.w};
    float ta[8] = {t0.x, t0.y, t0.z, t0.w, t1.x, t1.y, t1.z, t1.w};
    u16x8 z = *(const u16x8*)(Z + (size_t)idx * 8);
    u16x8 o;
#pragma unroll
    for (int j = 0; j < 8; ++j)
        o.v[j] = f2b(fmaxf(fmaf(sa[j], b2f(z.v[j]), ta[j]), 0.f));
    *(u16x8*)(Z + (size_t)idx * 8) = o;
}

// ---------------- column stats (layer 3 only) ----------------

__global__ void stats_kernel(const u16* __restrict__ Z, int F, float* __restrict__ sums) {
    int f = threadIdx.x;
    float s = 0.f, q = 0.f;
    for (int r = blockIdx.x; r < NN; r += gridDim.x) {
        float v = b2f(Z[(size_t)r * F + f]);
        s += v;
        q += v * v;
    }
    atomicAdd(&sums[f], s);
    atomicAdd(&sums[F + f], q);
}

__global__ void finalize_kernel(const float* __restrict__ sums, int F,
                                const float* __restrict__ g, const float* __restrict__ be,
                                float* __restrict__ sc, float* __restrict__ shf) {
    int f = threadIdx.x;
    if (f < F) {
        float m = sums[f] * (1.f / NN);
        float v = sums[F + f] * (1.f / NN) - m * m;
        float s = g[f] * rsqrtf(v + EPSB);
        sc[f] = s;
        shf[f] = be[f] - m * s;
    }
}

// ---------------- pool ----------------

__global__ void pool_kernel(const u16* __restrict__ Z, const int* __restrict__ batch,
                            const float* __restrict__ sc, const float* __restrict__ shf,
                            float* __restrict__ out) {
    int gph = blockIdx.x;
    int f = threadIdx.x;   // 128
    __shared__ int sb, se;
    if (f == 0) {
        int lo = 0, hi = NN;
        while (lo < hi) { int mid = (lo + hi) >> 1; if (batch[mid] < gph) lo = mid + 1; else hi = mid; }
        sb = lo;
        hi = NN;
        while (lo < hi) { int mid = (lo + hi) >> 1; if (batch[mid] < gph + 1) lo = mid + 1; else hi = mid; }
        se = lo;
    }
    __syncthreads();
    int beg = sb, end = se;
    float acc = 0.f;
    for (int r = beg; r < end; ++r) acc += b2f(Z[(size_t)r * 128 + f]);
    float res = 0.f;
    int c = end - beg;
    if (c > 0) res = fmaf(sc[f], acc / (float)c, shf[f]);
    out[(size_t)gph * 128 + f] = res;
}

// ---------------- launch ----------------

extern "C" void kernel_launch(void* const* d_in, const int* in_sizes, int n_in,
                              void* d_out, int out_size, void* d_ws, size_t ws_size,
                              hipStream_t stream) {
    const float* x     = (const float*)d_in[0];
    const int*   row   = (const int*)d_in[1];
    const int*   col   = (const int*)d_in[2];
    const int*   batch = (const int*)d_in[3];
    const float* W1 = (const float*)d_in[4];
    const float* g1 = (const float*)d_in[6];
    const float* be1 = (const float*)d_in[7];
    const float* W2 = (const float*)d_in[8];
    const float* g2 = (const float*)d_in[10];
    const float* be2 = (const float*)d_in[11];
    const float* W3 = (const float*)d_in[12];
    const float* g3 = (const float*)d_in[14];
    const float* be3 = (const float*)d_in[15];
    float* out = (float*)d_out;

    char* ws = (char*)d_ws;
    size_t off = 0;
    auto alloc = [&](size_t bytes) { size_t o = off; off += (bytes + 255) & ~255ULL; return o; };
    u16*   bufA   = (u16*)  (ws + alloc((size_t)MP * 256 * 2));   // T1 / T2 / H3
    u16*   bufB   = (u16*)  (ws + alloc((size_t)MP * 256 * 2));   // Z1->H1 / Z2->H2
    u16*   xb     = (u16*)  (ws + alloc((size_t)MP * 128 * 2));   // x bf16, later Z3
    u16*   Wt1    = (u16*)  (ws + alloc(128 * 256 * 2));
    u16*   Wt2    = (u16*)  (ws + alloc(256 * 256 * 2));
    u16*   Wt3    = (u16*)  (ws + alloc(256 * 128 * 2));
    int*   cnt    = (int*)  (ws + alloc((size_t)NN * 4));
    int*   colptr = (int*)  (ws + alloc((size_t)(NN + 1) * 4));
    int*   cursor = (int*)  (ws + alloc((size_t)NN * 4));
    float* dinv   = (float*)(ws + alloc((size_t)NN * 4));
    int*   srcs   = (int*)  (ws + alloc((size_t)EE * 4));
    int*   bsums  = (int*)  (ws + alloc(1024 * 4));
    float* stats  = (float*)(ws + alloc(6 * 256 * 4));
    float* scbuf  = (float*)(ws + alloc(6 * 256 * 4));
    float* gs     = (float*)(ws + alloc((size_t)MBLK * 2 * 256 * 4));

    hipMemsetAsync(cnt, 0, (size_t)NN * 4, stream);
    hipMemsetAsync(stats, 0, 6 * 256 * 4, stream);
    // zero A pad rows for both layouts (exact-zero contribution to fused stats)
    hipMemsetAsync((char*)bufA + (size_t)NN * 256, 0, (size_t)(MP - NN) * 256, stream);
    hipMemsetAsync((char*)bufA + (size_t)NN * 512, 0, (size_t)(MP - NN) * 512, stream);

    const int nScanBlocks = (NN + 255) / 256;
    count_kernel<<<(EE + 255) / 256, 256, 0, stream>>>(col, cnt);
    scanA_kernel<<<nScanBlocks, 256, 0, stream>>>(colptr, cnt, bsums, NN);
    scanB_kernel<<<1, 512, 0, stream>>>(bsums, nScanBlocks);
    scanC_kernel<<<nScanBlocks, 256, 0, stream>>>(colptr, bsums, cursor, cnt, dinv, NN);
    fill_kernel<<<(EE + 255) / 256, 256, 0, stream>>>(row, col, cursor, srcs);

    xcast_kernel<<<(NN * 32 + 255) / 256, 256, 0, stream>>>(x, xb);
    wcast_kernel<<<(128 * 256 + 255) / 256, 256, 0, stream>>>(W1, Wt1, 128, 256);
    wcast_kernel<<<(256 * 256 + 255) / 256, 256, 0, stream>>>(W2, Wt2, 256, 256);
    wcast_kernel<<<(256 * 128 + 255) / 256, 256, 0, stream>>>(W3, Wt3, 256, 128);

    const int aggBlocks = (NN + 3) / 4;

    // Layer 1
    agg_kernel<128><<<aggBlocks, 256, 0, stream>>>(xb, bufA, colptr, srcs, dinv);
    gemm_kernel<true><<<dim3(MBLK, 2), 256, 0, stream>>>(bufA, Wt1, bufB, 128, 256, gs);
    statreduce_kernel<<<dim3(2, 2), 128, 0, stream>>>(gs, stats + 0, 256);
    finalize_kernel<<<1, 256, 0, stream>>>(stats + 0, 256, g1, be1, scbuf + 0, scbuf + 256);

    // Layer 2
    hrelu_kernel<<<(NN * 32 + 255) / 256, 256, 0, stream>>>(bufB, scbuf + 0, scbuf + 256);
    agg_kernel<256><<<aggBlocks, 256, 0, stream>>>(bufB, bufA, colptr, srcs, dinv);
    gemm_kernel<true><<<dim3(MBLK, 2), 256, 0, stream>>>(bufA, Wt2, bufB, 256, 256, gs);
    statreduce_kernel<<<dim3(2, 2), 128, 0, stream>>>(gs, stats + 512, 256);
    finalize_kernel<<<1, 256, 0, stream>>>(stats + 512, 256, g2, be2, scbuf + 512, scbuf + 768);

    // Layer 3
    hrelu_kernel<<<(NN * 32 + 255) / 256, 256, 0, stream>>>(bufB, scbuf + 512, scbuf + 768);
    gemm_kernel<false><<<dim3(MBLK, 1), 256, 0, stream>>>(bufB, Wt3, bufA, 256, 128, gs);
    agg_kernel<128><<<aggBlocks, 256, 0, stream>>>(bufA, xb, colptr, srcs, dinv);
    stats_kernel<<<512, 128, 0, stream>>>(xb, 128, stats + 1024);
    finalize_kernel<<<1, 256, 0, stream>>>(stats + 1024, 128, g3, be3, scbuf + 1024, scbuf + 1280);

    pool_kernel<<<GG, 128, 0, stream>>>(xb, batch, scbuf + 1024, scbuf + 1280, out);
}

// Round 4
// 714.076 us; speedup vs baseline: 2.0784x; 1.0117x over previous
//
#include <hip/hip_runtime.h>

#define NN 100000
#define EE 1600000
#define GG 2048
#define EPSB 1e-5f
#define MP 100096        // NN padded to multiple of 128
#define MBLK (MP / 128)  // 782
#define NB 782           // buckets of 128 dest nodes

typedef unsigned short u16;
typedef unsigned long long u64;
typedef __attribute__((ext_vector_type(8))) short short8;
typedef __attribute__((ext_vector_type(4))) float f32x4;

struct alignas(4)  u16x2 { u16 v[2]; };
struct alignas(8)  u16x4 { u16 v[4]; };
struct alignas(16) u16x8 { u16 v[8]; };

__device__ __forceinline__ float b2f(u16 u) { return __uint_as_float(((unsigned)u) << 16); }
__device__ __forceinline__ u16 f2b(float f) {
    unsigned u = __float_as_uint(f);
    return (u16)((u + 0x7FFF + ((u >> 16) & 1)) >> 16);
}
__device__ __forceinline__ void gload16(const void* g, void* l) {
    __builtin_amdgcn_global_load_lds((const __attribute__((address_space(1))) void*)g,
                                     (__attribute__((address_space(3))) void*)l, 16, 0, 0);
}

// ---------------- CSR build ----------------

__global__ void count_kernel(const int* __restrict__ col, int* __restrict__ cnt) {
    int e = blockIdx.x * 256 + threadIdx.x;
    if (e < EE) atomicAdd(&cnt[col[e]], 1);
}

__global__ void scanA_kernel(int* __restrict__ colptr, const int* __restrict__ cnt,
                             int* __restrict__ bsums, int n) {
    __shared__ int sh[256];
    int t = threadIdx.x;
    int i = blockIdx.x * 256 + t;
    int v = (i < n) ? cnt[i] : 0;
    sh[t] = v;
    __syncthreads();
    for (int off = 1; off < 256; off <<= 1) {
        int u = (t >= off) ? sh[t - off] : 0;
        __syncthreads();
        sh[t] += u;
        __syncthreads();
    }
    if (i < n) colptr[i] = sh[t] - v;
    if (t == 255) bsums[blockIdx.x] = sh[255];
}

__global__ void scanB_kernel(int* __restrict__ bsums, int nb) {
    __shared__ int sh[512];
    int t = threadIdx.x;
    int v = (t < nb) ? bsums[t] : 0;
    sh[t] = v;
    __syncthreads();
    for (int off = 1; off < 512; off <<= 1) {
        int u = (t >= off) ? sh[t - off] : 0;
        __syncthreads();
        sh[t] += u;
        __syncthreads();
    }
    if (t < nb) bsums[t] = sh[t] - v;
}

__global__ void scanC_kernel(int* __restrict__ colptr, const int* __restrict__ bsums,
                             const int* __restrict__ cnt, float* __restrict__ dinv,
                             int* __restrict__ bcur, int n) {
    int i = blockIdx.x * 256 + threadIdx.x;
    if (i < n) {
        int v = colptr[i] + bsums[blockIdx.x];
        colptr[i] = v;
        dinv[i] = rsqrtf((float)(cnt[i] + 1));
        if ((i & 127) == 0) bcur[(i >> 7) * 16] = v;   // bucket cursor (line-padded)
    }
    if (i == 0) colptr[n] = EE;
}

// pass A: bucket edges by col>>7, appending packed (row,col)
__global__ void bucketA_kernel(const int* __restrict__ row, const int* __restrict__ col,
                               int* __restrict__ bcur, u64* __restrict__ bkt) {
    int e = blockIdx.x * 256 + threadIdx.x;
    if (e < EE) {
        int c = col[e], r = row[e];
        int p = atomicAdd(&bcur[(c >> 7) * 16], 1);
        bkt[p] = ((u64)r << 32) | (unsigned)c;
    }
}

// pass B: fine scatter within each bucket's contiguous CSR region
__global__ void bucketB_kernel(const u64* __restrict__ bkt, const int* __restrict__ colptr,
                               int* __restrict__ srcs) {
    int b = blockIdx.x;          // 0..NB-1
    int n0 = b << 7;
    int nend = n0 + 128;
    if (nend > NN) nend = NN;
    __shared__ int cur[128];
    int t = threadIdx.x;         // 256
    if (t < 128 && n0 + t < NN) cur[t] = colptr[n0 + t];
    __syncthreads();
    int beg = colptr[n0];
    int end = colptr[nend];
    for (int i = beg + t; i < end; i += 256) {
        u64 v = bkt[i];
        int c = (int)(v & 0xffffffffu);
        int r = (int)(v >> 32);
        int p = atomicAdd(&cur[c & 127], 1);
        srcs[p] = r;
    }
}

// ---------------- casts ----------------

__global__ void xcast_kernel(const float* __restrict__ x, u16* __restrict__ xb) {
    int idx = blockIdx.x * 256 + threadIdx.x;
    if (idx < NN * 32) {
        float4 v = ((const float4*)x)[idx];
        u16x4 o = {{f2b(v.x), f2b(v.y), f2b(v.z), f2b(v.w)}};
        ((u16x4*)xb)[idx] = o;
    }
}

// Wt[n*K + k] = bf16(W[k*Nout + n])
__global__ void wcast_kernel(const float* __restrict__ W, u16* __restrict__ Wt, int K, int Nout) {
    int idx = blockIdx.x * 256 + threadIdx.x;
    if (idx < K * Nout) {
        int n = idx / K;
        int k = idx - n * K;
        Wt[idx] = f2b(W[(size_t)k * Nout + n]);
    }
}

// ---------------- aggregation (one node per wave, shfl-batched, 8-deep MLP) ----------------
// out[i] = dinv[i] * ( sum_e dinv[src_e]*X[src_e] + dinv[i]*X[i] )

template <int F>
__global__ void agg_kernel(const u16* __restrict__ X, u16* __restrict__ out,
                           const int* __restrict__ colptr, const int* __restrict__ srcs,
                           const float* __restrict__ dinv) {
    constexpr int VE = F / 64;   // 4 (F=256) or 2 (F=128)
    int node = blockIdx.x * 4 + (threadIdx.x >> 6);
    if (node >= NN) return;
    int l = threadIdx.x & 63;
    int f0 = l * VE;
    float acc[VE] = {};
    int beg = colptr[node], end = colptr[node + 1];

    auto fetch = [&](int s, u16* u) {
        if (VE == 4) *(u16x4*)u = *(const u16x4*)(X + (size_t)s * F + f0);
        else         *(u16x2*)u = *(const u16x2*)(X + (size_t)s * F + f0);
    };
    auto accum = [&](const u16* u, float w) {
#pragma unroll
        for (int j = 0; j < VE; ++j) acc[j] = fmaf(w, b2f(u[j]), acc[j]);
    };

    for (int e0 = beg; e0 < end; e0 += 64) {
        int take = end - e0;
        if (take > 64) take = 64;
        int sv = 0;
        float wv = 0.f;
        if (l < take) { sv = srcs[e0 + l]; wv = dinv[sv]; }
        int j = 0;
        for (; j + 7 < take; j += 8) {
            int s[8];
            float w[8];
            u16 u[8][VE];
#pragma unroll
            for (int q = 0; q < 8; ++q) {
                s[q] = __shfl(sv, j + q);
                w[q] = __shfl(wv, j + q);
            }
#pragma unroll
            for (int q = 0; q < 8; ++q) fetch(s[q], u[q]);
#pragma unroll
            for (int q = 0; q < 8; ++q) accum(u[q], w[q]);
        }
        for (; j < take; ++j) {
            int s0 = __shfl(sv, j);
            float w0 = __shfl(wv, j);
            u16 u0[VE];
            fetch(s0, u0);
            accum(u0, w0);
        }
    }
    float di = dinv[node];
    u16 us[VE];
    fetch(node, us);
    accum(us, di);
    if (VE == 4) {
        u16x4 o = {{f2b(di * acc[0]), f2b(di * acc[1]), f2b(di * acc[2]), f2b(di * acc[3])}};
        *(u16x4*)(out + (size_t)node * F + f0) = o;
    } else {
        u16x2 o = {{f2b(di * acc[0]), f2b(di * acc[1])}};
        *(u16x2*)(out + (size_t)node * F + f0) = o;
    }
}

// ---------------- MFMA GEMM: C[MP,Nout](bf16) = A[MP,Kdim] @ Wt[Nout,Kdim]^T ----------------

template <bool STATS>
__global__ __launch_bounds__(256) void gemm_kernel(const u16* __restrict__ A,
                                                   const u16* __restrict__ Wt,
                                                   u16* __restrict__ C,
                                                   int Kdim, int Nout,
                                                   float* __restrict__ gs) {
    __shared__ u16 As[128 * 64];
    __shared__ u16 Bs[128 * 64];
    __shared__ float sbuf[2][128];
    const int tid = threadIdx.x;
    const int w = tid >> 6, l = tid & 63;
    const int row0 = blockIdx.x * 128;
    const int col0 = blockIdx.y * 128;
    const int srow = w * 32 + (l >> 3);
    const int skel = (l & 7) * 8;
    const u16* Asrc = A + (size_t)(row0 + srow) * Kdim + skel;
    const u16* Bsrc = Wt + (size_t)(col0 + srow) * Kdim + skel;
    u16* AsBase = &As[w * 2048];
    u16* BsBase = &Bs[w * 2048];
    const int wr = (w >> 1) * 64, wc = (w & 1) * 64;
    f32x4 acc[4][4] = {};
    if (STATS && tid < 128) { sbuf[0][tid] = 0.f; sbuf[1][tid] = 0.f; }

    for (int k0 = 0; k0 < Kdim; k0 += 64) {
#pragma unroll
        for (int j = 0; j < 4; ++j) {
            gload16(Asrc + (size_t)(j * 8) * Kdim + k0, AsBase + j * 512);
            gload16(Bsrc + (size_t)(j * 8) * Kdim + k0, BsBase + j * 512);
        }
        __syncthreads();
#pragma unroll
        for (int ks = 0; ks < 2; ++ks) {
            short8 a[4], b[4];
#pragma unroll
            for (int mi = 0; mi < 4; ++mi)
                a[mi] = *(const short8*)&As[(wr + mi * 16 + (l & 15)) * 64 + ks * 32 + (l >> 4) * 8];
#pragma unroll
            for (int ni = 0; ni < 4; ++ni)
                b[ni] = *(const short8*)&Bs[(wc + ni * 16 + (l & 15)) * 64 + ks * 32 + (l >> 4) * 8];
#pragma unroll
            for (int mi = 0; mi < 4; ++mi)
#pragma unroll
                for (int ni = 0; ni < 4; ++ni)
                    acc[mi][ni] = __builtin_amdgcn_mfma_f32_16x16x32_bf16(a[mi], b[ni], acc[mi][ni], 0, 0, 0);
        }
        __syncthreads();
    }
    const int cr = (l >> 4) * 4, cc = l & 15;
#pragma unroll
    for (int mi = 0; mi < 4; ++mi) {
#pragma unroll
        for (int j = 0; j < 4; ++j) {
            int r = row0 + wr + mi * 16 + cr + j;
#pragma unroll
            for (int ni = 0; ni < 4; ++ni)
                C[(size_t)r * Nout + col0 + wc + ni * 16 + cc] = f2b(acc[mi][ni][j]);
        }
    }
    if (STATS) {
#pragma unroll
        for (int ni = 0; ni < 4; ++ni) {
            float s = 0.f, q = 0.f;
#pragma unroll
            for (int mi = 0; mi < 4; ++mi)
#pragma unroll
                for (int jj = 0; jj < 4; ++jj) {
                    float v = acc[mi][ni][jj];
                    s += v;
                    q += v * v;
                }
            s += __shfl_xor(s, 16); s += __shfl_xor(s, 32);
            q += __shfl_xor(q, 16); q += __shfl_xor(q, 32);
            if (l < 16) {
                atomicAdd(&sbuf[0][wc + ni * 16 + l], s);
                atomicAdd(&sbuf[1][wc + ni * 16 + l], q);
            }
        }
        __syncthreads();
        if (tid < 128) {
            size_t base = (size_t)(blockIdx.y * gridDim.x + blockIdx.x) * 256;
            gs[base + tid] = sbuf[0][tid];
            gs[base + 128 + tid] = sbuf[1][tid];
        }
    }
}

__global__ void statreduce_kernel(const float* __restrict__ gs, float* __restrict__ sums, int F) {
    int which = blockIdx.x;
    int by = blockIdx.y;
    int c = threadIdx.x;
    float s = 0.f;
    for (int bx = 0; bx < MBLK; ++bx)
        s += gs[(size_t)(by * MBLK + bx) * 256 + which * 128 + c];
    sums[which * F + by * 128 + c] = s;
}

// ---------------- BN+ReLU materialization (in place) ----------------

__global__ void hrelu_kernel(u16* __restrict__ Z,
                             const float* __restrict__ sc, const float* __restrict__ shf) {
    int idx = blockIdx.x * 256 + threadIdx.x;
    if (idx >= NN * 32) return;
    int f0 = (idx & 31) * 8;
    float4 s0 = *(const float4*)&sc[f0], s1 = *(const float4*)&sc[f0 + 4];
    float4 t0 = *(const float4*)&shf[f0], t1 = *(const float4*)&shf[f0 + 4];
    float sa[8] = {s0.x, s0.y, s0.z, s0.w, s1.x, s1.y, s1.z, s1.w};
    float ta[8] = {t0.x, t0.y, t0.z, t0.w, t1.x, t1.y, t1.z, t1.w};
    u16x8 z = *(const u16x8*)(Z + (size_t)idx * 8);
    u16x8 o;
#pragma unroll
    for (int j = 0; j < 8; ++j)
        o.v[j] = f2b(fmaxf(fmaf(sa[j], b2f(z.v[j]), ta[j]), 0.f));
    *(u16x8*)(Z + (size_t)idx * 8) = o;
}

// ---------------- column stats (layer 3 only) ----------------

__global__ void stats_kernel(const u16* __restrict__ Z, int F, float* __restrict__ sums) {
    int f = threadIdx.x;
    float s = 0.f, q = 0.f;
    for (int r = blockIdx.x; r < NN; r += gridDim.x) {
        float v = b2f(Z[(size_t)r * F + f]);
        s += v;
        q += v * v;
    }
    atomicAdd(&sums[f], s);
    atomicAdd(&sums[F + f], q);
}

__global__ void finalize_kernel(const float* __restrict__ sums, int F,
                                const float* __restrict__ g, const float* __restrict__ be,
                                float* __restrict__ sc, float* __restrict__ shf) {
    int f = threadIdx.x;
    if (f < F) {
        float m = sums[f] * (1.f / NN);
        float v = sums[F + f] * (1.f / NN) - m * m;
        float s = g[f] * rsqrtf(v + EPSB);
        sc[f] = s;
        shf[f] = be[f] - m * s;
    }
}

// ---------------- pool ----------------

__global__ void pool_kernel(const u16* __restrict__ Z, const int* __restrict__ batch,
                            const float* __restrict__ sc, const float* __restrict__ shf,
                            float* __restrict__ out) {
    int gph = blockIdx.x;
    int f = threadIdx.x;
    __shared__ int sb, se;
    if (f == 0) {
        int lo = 0, hi = NN;
        while (lo < hi) { int mid = (lo + hi) >> 1; if (batch[mid] < gph) lo = mid + 1; else hi = mid; }
        sb = lo;
        hi = NN;
        while (lo < hi) { int mid = (lo + hi) >> 1; if (batch[mid] < gph + 1) lo = mid + 1; else hi = mid; }
        se = lo;
    }
    __syncthreads();
    int beg = sb, end = se;
    float acc = 0.f;
    for (int r = beg; r < end; ++r) acc += b2f(Z[(size_t)r * 128 + f]);
    float res = 0.f;
    int c = end - beg;
    if (c > 0) res = fmaf(sc[f], acc / (float)c, shf[f]);
    out[(size_t)gph * 128 + f] = res;
}

// ---------------- launch ----------------

extern "C" void kernel_launch(void* const* d_in, const int* in_sizes, int n_in,
                              void* d_out, int out_size, void* d_ws, size_t ws_size,
                              hipStream_t stream) {
    const float* x     = (const float*)d_in[0];
    const int*   row   = (const int*)d_in[1];
    const int*   col   = (const int*)d_in[2];
    const int*   batch = (const int*)d_in[3];
    const float* W1 = (const float*)d_in[4];
    const float* g1 = (const float*)d_in[6];
    const float* be1 = (const float*)d_in[7];
    const float* W2 = (const float*)d_in[8];
    const float* g2 = (const float*)d_in[10];
    const float* be2 = (const float*)d_in[11];
    const float* W3 = (const float*)d_in[12];
    const float* g3 = (const float*)d_in[14];
    const float* be3 = (const float*)d_in[15];
    float* out = (float*)d_out;

    char* ws = (char*)d_ws;
    size_t off = 0;
    auto alloc = [&](size_t bytes) { size_t o = off; off += (bytes + 255) & ~255ULL; return o; };
    u16*   bufA   = (u16*)  (ws + alloc((size_t)MP * 256 * 2));   // T1 / T2 / H3
    u16*   bufB   = (u16*)  (ws + alloc((size_t)MP * 256 * 2));   // Z1->H1 / Z2->H2
    u16*   xb     = (u16*)  (ws + alloc((size_t)MP * 128 * 2));   // x bf16, later Z3
    u16*   Wt1    = (u16*)  (ws + alloc(128 * 256 * 2));
    u16*   Wt2    = (u16*)  (ws + alloc(256 * 256 * 2));
    u16*   Wt3    = (u16*)  (ws + alloc(256 * 128 * 2));
    int*   cnt    = (int*)  (ws + alloc((size_t)NN * 4));
    int*   colptr = (int*)  (ws + alloc((size_t)(NN + 1) * 4));
    float* dinv   = (float*)(ws + alloc((size_t)NN * 4));
    int*   srcs   = (int*)  (ws + alloc((size_t)EE * 4));
    u64*   bkt    = (u64*)  (ws + alloc((size_t)EE * 8));
    int*   bcur   = (int*)  (ws + alloc((size_t)NB * 16 * 4));
    int*   bsums  = (int*)  (ws + alloc(1024 * 4));
    float* stats  = (float*)(ws + alloc(6 * 256 * 4));
    float* scbuf  = (float*)(ws + alloc(6 * 256 * 4));
    float* gs     = (float*)(ws + alloc((size_t)MBLK * 2 * 256 * 4));

    hipMemsetAsync(cnt, 0, (size_t)NN * 4, stream);
    hipMemsetAsync(stats, 0, 6 * 256 * 4, stream);
    // zero A pad rows (exact-zero contribution to fused stats)
    hipMemsetAsync((char*)bufA + (size_t)NN * 256, 0, (size_t)(MP - NN) * 256, stream);
    hipMemsetAsync((char*)bufA + (size_t)NN * 512, 0, (size_t)(MP - NN) * 512, stream);

    const int nScanBlocks = (NN + 255) / 256;
    count_kernel<<<(EE + 255) / 256, 256, 0, stream>>>(col, cnt);
    scanA_kernel<<<nScanBlocks, 256, 0, stream>>>(colptr, cnt, bsums, NN);
    scanB_kernel<<<1, 512, 0, stream>>>(bsums, nScanBlocks);
    scanC_kernel<<<nScanBlocks, 256, 0, stream>>>(colptr, bsums, cnt, dinv, bcur, NN);
    bucketA_kernel<<<(EE + 255) / 256, 256, 0, stream>>>(row, col, bcur, bkt);
    bucketB_kernel<<<NB, 256, 0, stream>>>(bkt, colptr, srcs);

    xcast_kernel<<<(NN * 32 + 255) / 256, 256, 0, stream>>>(x, xb);
    wcast_kernel<<<(128 * 256 + 255) / 256, 256, 0, stream>>>(W1, Wt1, 128, 256);
    wcast_kernel<<<(256 * 256 + 255) / 256, 256, 0, stream>>>(W2, Wt2, 256, 256);
    wcast_kernel<<<(256 * 128 + 255) / 256, 256, 0, stream>>>(W3, Wt3, 256, 128);

    const int aggBlocks = (NN + 3) / 4;

    // Layer 1
    agg_kernel<128><<<aggBlocks, 256, 0, stream>>>(xb, bufA, colptr, srcs, dinv);
    gemm_kernel<true><<<dim3(MBLK, 2), 256, 0, stream>>>(bufA, Wt1, bufB, 128, 256, gs);
    statreduce_kernel<<<dim3(2, 2), 128, 0, stream>>>(gs, stats + 0, 256);
    finalize_kernel<<<1, 256, 0, stream>>>(stats + 0, 256, g1, be1, scbuf + 0, scbuf + 256);

    // Layer 2
    hrelu_kernel<<<(NN * 32 + 255) / 256, 256, 0, stream>>>(bufB, scbuf + 0, scbuf + 256);
    agg_kernel<256><<<aggBlocks, 256, 0, stream>>>(bufB, bufA, colptr, srcs, dinv);
    gemm_kernel<true><<<dim3(MBLK, 2), 256, 0, stream>>>(bufA, Wt2, bufB, 256, 256, gs);
    statreduce_kernel<<<dim3(2, 2), 128, 0, stream>>>(gs, stats + 512, 256);
    finalize_kernel<<<1, 256, 0, stream>>>(stats + 512, 256, g2, be2, scbuf + 512, scbuf + 768);

    // Layer 3
    hrelu_kernel<<<(NN * 32 + 255) / 256, 256, 0, stream>>>(bufB, scbuf + 512, scbuf + 768);
    gemm_kernel<false><<<dim3(MBLK, 1), 256, 0, stream>>>(bufB, Wt3, bufA, 256, 128, gs);
    agg_kernel<128><<<aggBlocks, 256, 0, stream>>>(bufA, xb, colptr, srcs, dinv);
    stats_kernel<<<512, 128, 0, stream>>>(xb, 128, stats + 1024);
    finalize_kernel<<<1, 256, 0, stream>>>(stats + 1024, 128, g3, be3, scbuf + 1024, scbuf + 1280);

    pool_kernel<<<GG, 128, 0, stream>>>(xb, batch, scbuf + 1024, scbuf + 1280, out);
}

// Round 5
// 611.418 us; speedup vs baseline: 2.4274x; 1.1679x over previous
//
#include <hip/hip_runtime.h>

#define NN 100000
#define EE 1600000
#define GG 2048
#define EPSB 1e-5f
#define MP 100096        // NN padded to multiple of 128
#define MBLK (MP / 128)  // 782
#define NB 782           // buckets of 128 dest nodes
#define CAP 2560         // bucket capacity (mean 2046, sd ~45)

typedef unsigned short u16;
typedef unsigned long long u64;
typedef __attribute__((ext_vector_type(8))) short short8;
typedef __attribute__((ext_vector_type(4))) float f32x4;

struct alignas(4)  u16x2 { u16 v[2]; };
struct alignas(8)  u16x4 { u16 v[4]; };
struct alignas(16) u16x8 { u16 v[8]; };

__device__ __forceinline__ float b2f(u16 u) { return __uint_as_float(((unsigned)u) << 16); }
__device__ __forceinline__ u16 f2b(float f) {
    unsigned u = __float_as_uint(f);
    return (u16)((u + 0x7FFF + ((u >> 16) & 1)) >> 16);
}
__device__ __forceinline__ void gload16(const void* g, void* l) {
    __builtin_amdgcn_global_load_lds((const __attribute__((address_space(1))) void*)g,
                                     (__attribute__((address_space(3))) void*)l, 16, 0, 0);
}

// ---------------- CSR build (bucketed, no global count/scan prepass) ----------------

// pass A: append (row,col) into fixed-capacity bucket col>>7
__global__ void bucketA_kernel(const int* __restrict__ row, const int* __restrict__ col,
                               int* __restrict__ bcur, u64* __restrict__ bkt) {
    int e = blockIdx.x * 256 + threadIdx.x;
    if (e < EE) {
        int c = col[e], r = row[e];
        int b = c >> 7;
        int p = atomicAdd(&bcur[b * 16], 1);
        if (p < CAP) bkt[(size_t)b * CAP + p] = ((u64)r << 32) | (unsigned)c;
    }
}

// pass B: per-bucket node counts, dinv, padded-count local exclusive scan, bucket total
__global__ void bucketB_kernel(const u64* __restrict__ bkt, const int* __restrict__ bcur,
                               int* __restrict__ pfx, int* __restrict__ rcnt,
                               float* __restrict__ dinv, int* __restrict__ btot) {
    int b = blockIdx.x, t = threadIdx.x;   // 256 threads
    __shared__ int lcnt[128];
    __shared__ int sp[128];
    if (t < 128) lcnt[t] = 0;
    __syncthreads();
    int tot = bcur[b * 16];
    if (tot > CAP) tot = CAP;
    const u64* B = bkt + (size_t)b * CAP;
    for (int i = t; i < tot; i += 256) atomicAdd(&lcnt[(int)(B[i] & 127)], 1);
    __syncthreads();
    int n0 = b << 7;
    int pc = 0;
    if (t < 128) {
        int c = lcnt[t];
        if (n0 + t < NN) dinv[n0 + t] = rsqrtf((float)(c + 1));
        rcnt[b * 128 + t] = c;
        pc = (c + 7) & ~7;
        sp[t] = pc;
    }
    __syncthreads();
    for (int o = 1; o < 128; o <<= 1) {
        int u = (t >= o && t < 128) ? sp[t - o] : 0;
        __syncthreads();
        if (t < 128) sp[t] += u;
        __syncthreads();
    }
    if (t < 128) pfx[b * 128 + t] = sp[t] - pc;
    if (t == 127) btot[b] = sp[127];
}

// tiny scan over 782 bucket totals -> bases (in place); also dinv[NN]=0, colptr[NN]=total
__global__ void scanT_kernel(int* __restrict__ btot, float* __restrict__ dinv,
                             int* __restrict__ colptr) {
    __shared__ int sh[1024];
    int t = threadIdx.x;
    int v = (t < NB) ? btot[t] : 0;
    sh[t] = v;
    __syncthreads();
    for (int o = 1; o < 1024; o <<= 1) {
        int u = (t >= o) ? sh[t - o] : 0;
        __syncthreads();
        sh[t] += u;
        __syncthreads();
    }
    if (t < NB) btot[t] = sh[t] - v;
    if (t == NB - 1) colptr[NN] = sh[t];
    if (t == 0) dinv[NN] = 0.f;
}

// pass C: local scatter + dummy padding + colptr
__global__ void bucketC_kernel(const u64* __restrict__ bkt, const int* __restrict__ bcur,
                               const int* __restrict__ pfx, const int* __restrict__ rcnt,
                               const int* __restrict__ btot, int* __restrict__ colptr,
                               int* __restrict__ srcs) {
    int b = blockIdx.x, t = threadIdx.x;
    int n0 = b << 7;
    __shared__ int cur[128];
    int base = btot[b];
    if (t < 128) {
        int st = base + pfx[b * 128 + t];
        cur[t] = st;
        if (n0 + t < NN) colptr[n0 + t] = st;
    }
    __syncthreads();
    int tot = bcur[b * 16];
    if (tot > CAP) tot = CAP;
    const u64* B = bkt + (size_t)b * CAP;
    for (int i = t; i < tot; i += 256) {
        u64 v = B[i];
        int c = (int)(v & 127);
        int r = (int)(v >> 32);
        int p = atomicAdd(&cur[c], 1);
        srcs[p] = r;
    }
    __syncthreads();
    if (t < 128) {
        int rc = rcnt[b * 128 + t];
        int pc = (rc + 7) & ~7;
        int st = base + pfx[b * 128 + t];
        for (int i = rc; i < pc; ++i) srcs[st + i] = NN;   // dummy: w=dinv[NN]=0, X[NN]=0
    }
}

// ---------------- casts ----------------

__global__ void xcast_kernel(const float* __restrict__ x, u16* __restrict__ xb) {
    int idx = blockIdx.x * 256 + threadIdx.x;
    if (idx < NN * 32) {
        float4 v = ((const float4*)x)[idx];
        u16x4 o = {{f2b(v.x), f2b(v.y), f2b(v.z), f2b(v.w)}};
        ((u16x4*)xb)[idx] = o;
    }
}

__global__ void wcast_kernel(const float* __restrict__ W1, const float* __restrict__ W2,
                             const float* __restrict__ W3, u16* __restrict__ Wt1,
                             u16* __restrict__ Wt2, u16* __restrict__ Wt3) {
    int idx = blockIdx.x * 256 + threadIdx.x;
    if (idx < 32768) {            // Wt1[n*128+k] = W1[k*256+n]
        int n = idx >> 7, k = idx & 127;
        Wt1[idx] = f2b(W1[k * 256 + n]);
    } else if (idx < 98304) {     // Wt2[n*256+k] = W2[k*256+n]
        int j = idx - 32768;
        int n = j >> 8, k = j & 255;
        Wt2[j] = f2b(W2[k * 256 + n]);
    } else if (idx < 131072) {    // Wt3[n*256+k] = W3[k*128+n]
        int j = idx - 98304;
        int n = j >> 8, k = j & 255;
        Wt3[j] = f2b(W3[k * 128 + n]);
    }
}

// ---------------- aggregation (one node per wave; lists padded to multiples of 8) ----------------
// out[i] = dinv[i] * ( sum_e dinv[src_e]*f(X[src_e]) + dinv[i]*f(X[i]) ); f = id or relu(s*z+t)

template <int F, bool TR>
__global__ void agg_kernel(const u16* __restrict__ X, u16* __restrict__ out,
                           const int* __restrict__ colptr, const int* __restrict__ srcs,
                           const float* __restrict__ dinv,
                           const float* __restrict__ sc, const float* __restrict__ shf) {
    constexpr int VE = F / 64;   // 4 (F=256) or 2 (F=128)
    int node = blockIdx.x * 4 + (threadIdx.x >> 6);
    if (node >= NN) return;
    int l = threadIdx.x & 63;
    int f0 = l * VE;
    float s_[VE], t_[VE];
    if (TR) {
#pragma unroll
        for (int j = 0; j < VE; ++j) { s_[j] = sc[f0 + j]; t_[j] = shf[f0 + j]; }
    }
    float acc[VE] = {};
    int beg = colptr[node], end = colptr[node + 1];

    auto fetch = [&](int s, u16* u) {
        if (VE == 4) *(u16x4*)u = *(const u16x4*)(X + (size_t)s * F + f0);
        else         *(u16x2*)u = *(const u16x2*)(X + (size_t)s * F + f0);
    };
    auto accum = [&](const u16* u, float w) {
#pragma unroll
        for (int j = 0; j < VE; ++j) {
            float v = b2f(u[j]);
            if (TR) v = fmaxf(fmaf(s_[j], v, t_[j]), 0.f);
            acc[j] = fmaf(w, v, acc[j]);
        }
    };

    for (int e0 = beg; e0 < end; e0 += 64) {
        int take = end - e0;
        if (take > 64) take = 64;      // always a multiple of 8
        int sv = (l < take) ? srcs[e0 + l] : NN;
        float wv = dinv[sv];
        for (int j = 0; j < take; j += 8) {
            int s[8];
            float w[8];
            u16 u[8][VE];
#pragma unroll
            for (int q = 0; q < 8; ++q) {
                s[q] = __shfl(sv, j + q);
                w[q] = __shfl(wv, j + q);
            }
#pragma unroll
            for (int q = 0; q < 8; ++q) fetch(s[q], u[q]);
#pragma unroll
            for (int q = 0; q < 8; ++q) accum(u[q], w[q]);
        }
    }
    float di = dinv[node];
    u16 us[VE];
    fetch(node, us);
    accum(us, di);
    if (VE == 4) {
        u16x4 o = {{f2b(di * acc[0]), f2b(di * acc[1]), f2b(di * acc[2]), f2b(di * acc[3])}};
        *(u16x4*)(out + (size_t)node * F + f0) = o;
    } else {
        u16x2 o = {{f2b(di * acc[0]), f2b(di * acc[1])}};
        *(u16x2*)(out + (size_t)node * F + f0) = o;
    }
}

// ---------------- MFMA GEMM: C[MP,Nout](bf16) = f(A[MP,Kdim]) @ Wt[Nout,Kdim]^T ----------------
// STATS: emit per-block column (sum,sumsq) partials of fp32 accumulators.
// FUSEA: apply relu(sc*a+shf) to A during (reg-staged) LDS staging.

template <bool STATS, bool FUSEA>
__global__ __launch_bounds__(256) void gemm_kernel(const u16* __restrict__ A,
                                                   const u16* __restrict__ Wt,
                                                   u16* __restrict__ C,
                                                   int Kdim, int Nout,
                                                   float* __restrict__ gs,
                                                   const float* __restrict__ sc,
                                                   const float* __restrict__ shf) {
    __shared__ u16 As[128 * 64];
    __shared__ u16 Bs[128 * 64];
    __shared__ float sbuf[2][128];
    const int tid = threadIdx.x;
    const int w = tid >> 6, l = tid & 63;
    const int row0 = blockIdx.x * 128;
    const int col0 = blockIdx.y * 128;
    const int srow = w * 32 + (l >> 3);
    const int skel = (l & 7) * 8;
    const u16* Asrc = A + (size_t)(row0 + srow) * Kdim + skel;
    const u16* Bsrc = Wt + (size_t)(col0 + srow) * Kdim + skel;
    u16* AsBase = &As[w * 2048];
    u16* BsBase = &Bs[w * 2048];
    const int wr = (w >> 1) * 64, wc = (w & 1) * 64;
    f32x4 acc[4][4] = {};
    if (STATS && tid < 128) { sbuf[0][tid] = 0.f; sbuf[1][tid] = 0.f; }

    for (int k0 = 0; k0 < Kdim; k0 += 64) {
        if (FUSEA) {
            float4 sa0 = *(const float4*)&sc[k0 + skel];
            float4 sa1 = *(const float4*)&sc[k0 + skel + 4];
            float4 ta0 = *(const float4*)&shf[k0 + skel];
            float4 ta1 = *(const float4*)&shf[k0 + skel + 4];
            float sA[8] = {sa0.x, sa0.y, sa0.z, sa0.w, sa1.x, sa1.y, sa1.z, sa1.w};
            float tA[8] = {ta0.x, ta0.y, ta0.z, ta0.w, ta1.x, ta1.y, ta1.z, ta1.w};
#pragma unroll
            for (int j = 0; j < 4; ++j) {
                u16x8 av = *(const u16x8*)(Asrc + (size_t)(j * 8) * Kdim + k0);
                u16x8 o;
#pragma unroll
                for (int i = 0; i < 8; ++i)
                    o.v[i] = f2b(fmaxf(fmaf(sA[i], b2f(av.v[i]), tA[i]), 0.f));
                *(u16x8*)&As[(w * 32 + j * 8 + (l >> 3)) * 64 + skel] = o;
            }
        } else {
#pragma unroll
            for (int j = 0; j < 4; ++j)
                gload16(Asrc + (size_t)(j * 8) * Kdim + k0, AsBase + j * 512);
        }
#pragma unroll
        for (int j = 0; j < 4; ++j)
            gload16(Bsrc + (size_t)(j * 8) * Kdim + k0, BsBase + j * 512);
        __syncthreads();
#pragma unroll
        for (int ks = 0; ks < 2; ++ks) {
            short8 a[4], b[4];
#pragma unroll
            for (int mi = 0; mi < 4; ++mi)
                a[mi] = *(const short8*)&As[(wr + mi * 16 + (l & 15)) * 64 + ks * 32 + (l >> 4) * 8];
#pragma unroll
            for (int ni = 0; ni < 4; ++ni)
                b[ni] = *(const short8*)&Bs[(wc + ni * 16 + (l & 15)) * 64 + ks * 32 + (l >> 4) * 8];
#pragma unroll
            for (int mi = 0; mi < 4; ++mi)
#pragma unroll
                for (int ni = 0; ni < 4; ++ni)
                    acc[mi][ni] = __builtin_amdgcn_mfma_f32_16x16x32_bf16(a[mi], b[ni], acc[mi][ni], 0, 0, 0);
        }
        __syncthreads();
    }
    const int cr = (l >> 4) * 4, cc = l & 15;
#pragma unroll
    for (int mi = 0; mi < 4; ++mi) {
#pragma unroll
        for (int j = 0; j < 4; ++j) {
            int r = row0 + wr + mi * 16 + cr + j;
#pragma unroll
            for (int ni = 0; ni < 4; ++ni)
                C[(size_t)r * Nout + col0 + wc + ni * 16 + cc] = f2b(acc[mi][ni][j]);
        }
    }
    if (STATS) {
#pragma unroll
        for (int ni = 0; ni < 4; ++ni) {
            float s = 0.f, q = 0.f;
#pragma unroll
            for (int mi = 0; mi < 4; ++mi)
#pragma unroll
                for (int jj = 0; jj < 4; ++jj) {
                    float v = acc[mi][ni][jj];
                    s += v;
                    q += v * v;
                }
            s += __shfl_xor(s, 16); s += __shfl_xor(s, 32);
            q += __shfl_xor(q, 16); q += __shfl_xor(q, 32);
            if (l < 16) {
                atomicAdd(&sbuf[0][wc + ni * 16 + l], s);
                atomicAdd(&sbuf[1][wc + ni * 16 + l], q);
            }
        }
        __syncthreads();
        if (tid < 128) {
            size_t base = (size_t)(blockIdx.y * gridDim.x + blockIdx.x) * 256;
            gs[base + tid] = sbuf[0][tid];
            gs[base + 128 + tid] = sbuf[1][tid];
        }
    }
}

__global__ void statreduce_kernel(const float* __restrict__ gs, float* __restrict__ sums, int F) {
    int which = blockIdx.x;
    int by = blockIdx.y;
    int c = threadIdx.x;
    float s = 0.f;
    for (int bx = 0; bx < MBLK; ++bx)
        s += gs[(size_t)(by * MBLK + bx) * 256 + which * 128 + c];
    sums[which * F + by * 128 + c] = s;
}

// ---------------- column stats (layer 3 only) ----------------

__global__ void stats_kernel(const u16* __restrict__ Z, int F, float* __restrict__ sums) {
    int f = threadIdx.x;
    float s = 0.f, q = 0.f;
    for (int r = blockIdx.x; r < NN; r += gridDim.x) {
        float v = b2f(Z[(size_t)r * F + f]);
        s += v;
        q += v * v;
    }
    atomicAdd(&sums[f], s);
    atomicAdd(&sums[F + f], q);
}

__global__ void finalize_kernel(const float* __restrict__ sums, int F,
                                const float* __restrict__ g, const float* __restrict__ be,
                                float* __restrict__ sc, float* __restrict__ shf) {
    int f = threadIdx.x;
    if (f < F) {
        float m = sums[f] * (1.f / NN);
        float v = sums[F + f] * (1.f / NN) - m * m;
        float s = g[f] * rsqrtf(v + EPSB);
        sc[f] = s;
        shf[f] = be[f] - m * s;
    }
}

// ---------------- pool ----------------

__global__ void pool_kernel(const u16* __restrict__ Z, const int* __restrict__ batch,
                            const float* __restrict__ sc, const float* __restrict__ shf,
                            float* __restrict__ out) {
    int gph = blockIdx.x;
    int f = threadIdx.x;
    __shared__ int sb, se;
    if (f == 0) {
        int lo = 0, hi = NN;
        while (lo < hi) { int mid = (lo + hi) >> 1; if (batch[mid] < gph) lo = mid + 1; else hi = mid; }
        sb = lo;
        hi = NN;
        while (lo < hi) { int mid = (lo + hi) >> 1; if (batch[mid] < gph + 1) lo = mid + 1; else hi = mid; }
        se = lo;
    }
    __syncthreads();
    int beg = sb, end = se;
    float acc = 0.f;
    for (int r = beg; r < end; ++r) acc += b2f(Z[(size_t)r * 128 + f]);
    float res = 0.f;
    int c = end - beg;
    if (c > 0) res = fmaf(sc[f], acc / (float)c, shf[f]);
    out[(size_t)gph * 128 + f] = res;
}

// ---------------- launch ----------------

extern "C" void kernel_launch(void* const* d_in, const int* in_sizes, int n_in,
                              void* d_out, int out_size, void* d_ws, size_t ws_size,
                              hipStream_t stream) {
    const float* x     = (const float*)d_in[0];
    const int*   row   = (const int*)d_in[1];
    const int*   col   = (const int*)d_in[2];
    const int*   batch = (const int*)d_in[3];
    const float* W1 = (const float*)d_in[4];
    const float* g1 = (const float*)d_in[6];
    const float* be1 = (const float*)d_in[7];
    const float* W2 = (const float*)d_in[8];
    const float* g2 = (const float*)d_in[10];
    const float* be2 = (const float*)d_in[11];
    const float* W3 = (const float*)d_in[12];
    const float* g3 = (const float*)d_in[14];
    const float* be3 = (const float*)d_in[15];
    float* out = (float*)d_out;

    char* ws = (char*)d_ws;
    size_t off = 0;
    auto alloc = [&](size_t bytes) { size_t o = off; off += (bytes + 255) & ~255ULL; return o; };
    u16*   bufA   = (u16*)  (ws + alloc((size_t)MP * 256 * 2));   // T1 / T2 / H3
    u16*   bufB   = (u16*)  (ws + alloc((size_t)MP * 256 * 2));   // Z1 / Z2
    u16*   xb     = (u16*)  (ws + alloc((size_t)MP * 128 * 2));   // x bf16, later Z3
    u16*   Wt1    = (u16*)  (ws + alloc(128 * 256 * 2));
    u16*   Wt2    = (u16*)  (ws + alloc(256 * 256 * 2));
    u16*   Wt3    = (u16*)  (ws + alloc(256 * 128 * 2));
    int*   colptr = (int*)  (ws + alloc((size_t)(NN + 16) * 4));
    float* dinv   = (float*)(ws + alloc((size_t)(NN + 16) * 4));
    int*   srcs   = (int*)  (ws + alloc((size_t)(EE + 8 * NN) * 4));
    u64*   bkt    = (u64*)  (ws + alloc((size_t)NB * CAP * 8));
    int*   bcur   = (int*)  (ws + alloc((size_t)NB * 16 * 4));
    int*   pfx    = (int*)  (ws + alloc((size_t)NB * 128 * 4));
    int*   rcnt   = (int*)  (ws + alloc((size_t)NB * 128 * 4));
    int*   btot   = (int*)  (ws + alloc(1024 * 4));
    float* stats  = (float*)(ws + alloc(6 * 256 * 4));
    float* scbuf  = (float*)(ws + alloc(6 * 256 * 4));
    float* gs     = (float*)(ws + alloc((size_t)MBLK * 2 * 256 * 4));

    hipMemsetAsync(bcur, 0, (size_t)NB * 16 * 4, stream);
    hipMemsetAsync(stats, 0, 6 * 256 * 4, stream);
    // zero pad rows (exact-zero contribution to fused stats; zero dummy row NN)
    hipMemsetAsync((char*)bufA + (size_t)NN * 256, 0, (size_t)(MP - NN) * 256, stream);
    hipMemsetAsync((char*)bufA + (size_t)NN * 512, 0, (size_t)(MP - NN) * 512, stream);
    hipMemsetAsync((char*)xb + (size_t)NN * 256, 0, (size_t)(MP - NN) * 256, stream);

    bucketA_kernel<<<(EE + 255) / 256, 256, 0, stream>>>(row, col, bcur, bkt);
    bucketB_kernel<<<NB, 256, 0, stream>>>(bkt, bcur, pfx, rcnt, dinv, btot);
    scanT_kernel<<<1, 1024, 0, stream>>>(btot, dinv, colptr);
    bucketC_kernel<<<NB, 256, 0, stream>>>(bkt, bcur, pfx, rcnt, btot, colptr, srcs);

    xcast_kernel<<<(NN * 32 + 255) / 256, 256, 0, stream>>>(x, xb);
    wcast_kernel<<<512, 256, 0, stream>>>(W1, W2, W3, Wt1, Wt2, Wt3);

    const int aggBlocks = (NN + 3) / 4;

    // Layer 1: T1 = S@xb, Z1 = T1@W1 (stats fused)
    agg_kernel<128, false><<<aggBlocks, 256, 0, stream>>>(xb, bufA, colptr, srcs, dinv, nullptr, nullptr);
    gemm_kernel<true, false><<<dim3(MBLK, 2), 256, 0, stream>>>(bufA, Wt1, bufB, 128, 256, gs, nullptr, nullptr);
    statreduce_kernel<<<dim3(2, 2), 128, 0, stream>>>(gs, stats + 0, 256);
    finalize_kernel<<<1, 256, 0, stream>>>(stats + 0, 256, g1, be1, scbuf + 0, scbuf + 256);

    // Layer 2: T2 = S@relu(bn1(Z1)) (BN fused in gather), Z2 = T2@W2 (stats fused)
    agg_kernel<256, true><<<aggBlocks, 256, 0, stream>>>(bufB, bufA, colptr, srcs, dinv, scbuf + 0, scbuf + 256);
    gemm_kernel<true, false><<<dim3(MBLK, 2), 256, 0, stream>>>(bufA, Wt2, bufB, 256, 256, gs, nullptr, nullptr);
    statreduce_kernel<<<dim3(2, 2), 128, 0, stream>>>(gs, stats + 512, 256);
    finalize_kernel<<<1, 256, 0, stream>>>(stats + 512, 256, g2, be2, scbuf + 512, scbuf + 768);

    // Layer 3: H3 = relu(bn2(Z2))@W3 (BN fused in A-staging), Z3 = S@H3
    gemm_kernel<false, true><<<dim3(MBLK, 1), 256, 0, stream>>>(bufB, Wt3, bufA, 256, 128, gs, scbuf + 512, scbuf + 768);
    agg_kernel<128, false><<<aggBlocks, 256, 0, stream>>>(bufA, xb, colptr, srcs, dinv, nullptr, nullptr);
    stats_kernel<<<512, 128, 0, stream>>>(xb, 128, stats + 1024);
    finalize_kernel<<<1, 256, 0, stream>>>(stats + 1024, 128, g3, be3, scbuf + 1024, scbuf + 1280);

    pool_kernel<<<GG, 128, 0, stream>>>(xb, batch, scbuf + 1024, scbuf + 1280, out);
}